// Round 11
// baseline (217.249 us; speedup 1.0000x reference)
//
#include <hip/hip_runtime.h>
#include <hip/hip_bf16.h>
#include <hip/hip_cooperative_groups.h>

namespace cg = cooperative_groups;

// Problem constants (from reference)
#define E_TOTAL 300000
#define N_NODES 50000
#define NDIM    128      // node feature dim
#define KDIM    256      // 2*NDIM = GEMM K
#define HDIM    512      // 2*HIDDEN = GEMM N (both MLP branches fused)
#define BN_EPS  1e-5f
#define NTILES  ((E_TOTAL + 63) / 64)   // 4688 tiles of 64 edges
#define NBLK    256                      // persistent blocks, 1/CU (149KB LDS)
#define LT_MAX  19                       // max tiles per block
#define NF_F4   (N_NODES * NDIM / 4)     // 1.6M float4s total
#define NF_PER_BLK (NF_F4 / NBLK)        // 6250 float4s per block (exact)

typedef __attribute__((ext_vector_type(8))) short bf16x8;
typedef __attribute__((ext_vector_type(4))) float f32x4;
typedef const __attribute__((address_space(1))) unsigned int* gas1_t;
typedef __attribute__((address_space(3))) unsigned int* las3_t;

__device__ __forceinline__ unsigned short f2bf(float f) {
  unsigned u = __float_as_uint(f);
  u += 0x7fffu + ((u >> 16) & 1u);   // round-to-nearest-even
  return (unsigned short)(u >> 16);
}

// DPP rotate-add stage over all 16 partials (VALU pipe, zero LDS traffic).
#define DPP_STAGE(C)                                                          \
  {                                                                           \
    _Pragma("unroll")                                                         \
    for (int i = 0; i < 16; i++) {                                            \
      int t = __builtin_amdgcn_update_dpp(0, __float_as_int(vs[i]),           \
                                          (C), 0xF, 0xF, true);               \
      vs[i] += __int_as_float(t);                                             \
    }                                                                         \
  }

// ---- single COOPERATIVE kernel ----
// Phase 0: each block converts its nf slab fp32->bf16; blocks 0..31 build the
// BN-folded roll-fused W swizzle; block 32 cbias/w2c; idxl preload overlaps.
// grid.sync() (safe grid barrier). Phase 1: R8 main loop verbatim.
__global__ __launch_bounds__(512, 2) void edge_mlp_fused_kernel(
    const float* __restrict__ nf, const int* __restrict__ eidx,
    const float* __restrict__ W1, const float* __restrict__ b1,
    const float* __restrict__ gamma, const float* __restrict__ beta,
    const float* __restrict__ mean, const float* __restrict__ var,
    const float* __restrict__ W2, const float* __restrict__ b2,
    unsigned short* __restrict__ Wswz, float* __restrict__ cbias,
    float* __restrict__ w2c, unsigned short* __restrict__ nfb,
    float* __restrict__ out) {
  __shared__ unsigned short Ab[4][32 * 512];   // 128 KB
  __shared__ int idxl[LT_MAX * 128];           // 9.5 KB
  __shared__ float partial[4][8][64];          // 8 KB, ring by tile&3

  const int tid  = threadIdx.x;
  const int w    = tid >> 6;
  const int lane = tid & 63;
  const int l16  = lane & 15;
  const int quad = lane >> 4;
  const int b    = blockIdx.x;
  const int ntl  = (NTILES - b + NBLK - 1) / NBLK;   // 18 or 19

  // ---- Phase 0a: convert this block's nf slab (coalesced float4 -> ushort4) ----
  {
    const float4* src = (const float4*)nf;
    ushort4* dst = (ushort4*)nfb;
    int base = b * NF_PER_BLK;
    for (int i = tid; i < NF_PER_BLK; i += 512) {
      float4 v = src[base + i];
      ushort4 o;
      o.x = f2bf(v.x); o.y = f2bf(v.y); o.z = f2bf(v.z); o.w = f2bf(v.w);
      dst[base + i] = o;
    }
  }

  // ---- Phase 0b: weight swizzle (blocks 0..31), cbias/w2c (block 32) ----
  // Wswz frag (ct,kt): lane holds B[k = kt*32 + quad*8 + j][col = ct*16 + l16]
  // at Wswz[((ct*8+kt)*64+lane)*8]; col>=256 roll branch uses W1[(k+16)&255].
  if (b < 32) {
    int ct = b;
    int kt = tid >> 6;                 // 0..7
    int ln = tid & 63;
    int col = ct * 16 + (ln & 15);
    int qd  = ln >> 4;
    int jj  = col & 255;
    int shift = (col >= 256) ? 16 : 0;
    float s = gamma[jj] * rsqrtf(var[jj] + BN_EPS);
    unsigned short o[8];
    #pragma unroll
    for (int j = 0; j < 8; j++) {
      int k  = kt * 32 + qd * 8 + j;
      int ks = (k + shift) & 255;
      o[j] = f2bf(W1[ks * 256 + jj] * s);
    }
    *(uint4*)(Wswz + ((size_t)(ct * 8 + kt) * 64 + ln) * 8) = *(const uint4*)o;
  } else if (b == 32) {
    if (tid < HDIM) {
      int j = tid, jj = j & 255;
      float s = gamma[jj] * rsqrtf(var[jj] + BN_EPS);
      cbias[j] = b1[jj] * s + beta[jj] - mean[jj] * s;
      w2c[j]  = 0.5f * W2[jj];         // fold the 0.5 average
    }
  }

  // ---- Phase 0c: preload ALL this block's edge indices into LDS (overlaps) ----
  for (int g = tid; g < ntl * 128; g += 512) {
    int lt2 = g >> 7, r = g & 127;
    int half = r >> 6;
    int e = (b + lt2 * NBLK) * 64 + (r & 63);
    if (e >= E_TOTAL) e = E_TOTAL - 1;
    idxl[g] = eidx[half * E_TOTAL + e];
  }

  // ---- safe grid-wide barrier (cooperative launch) ----
  cg::this_grid().sync();

  // ---- B into registers: wave w -> ct = w*4 .. w*4+3 ----
  const bf16x8* Wf = (const bf16x8*)Wswz;
  bf16x8 bq[4][8];
  #pragma unroll
  for (int n = 0; n < 4; n++)
    #pragma unroll
    for (int kt = 0; kt < 8; kt++)
      bq[n][kt] = Wf[((w * 4 + n) * 8 + kt) * 64 + lane];

  float cj[4], w2j[4];
  #pragma unroll
  for (int n = 0; n < 4; n++) {
    int j = w * 64 + n * 16 + l16;
    cj[n]  = cbias[j];
    w2j[n] = w2c[j];
  }
  const float b2v = b2[0];

  // staging role (wave-constant): wave w stages frags f = sfrag0+i, i=0..3
  const int smt    = w & 3;
  const int shalf  = w >> 2;           // 0: row-node endpoint (k<128), 1: col-node
  const int sfrag0 = smt * 8 + shalf * 4;

  auto stage = [&](int lt2, int slot) {
    int node = idxl[lt2 * 128 + shalf * 64 + smt * 16 + l16];
    const unsigned short* gbase = nfb + (size_t)node * NDIM + quad * 8;
    // instr i: 4 same-edge lanes (quads) cover one contiguous 64B line
    #pragma unroll
    for (int i = 0; i < 4; i++)
      __builtin_amdgcn_global_load_lds((gas1_t)(gbase + i * 32),
                                       (las3_t)(&Ab[slot][(sfrag0 + i) * 512]),
                                       16, 0, 0);
  };

  auto combine = [&](int lt2, int le) {
    int e = (b + lt2 * NBLK) * 64 + le;
    if (e < E_TOTAL) {
      float s = 0.f;
      #pragma unroll
      for (int ww = 0; ww < 8; ww++) s += partial[lt2 & 3][ww][le];
      out[e] = 1.0f / (1.0f + __expf(-(s + b2v)));
    }
  };

  auto compute_tile = [&](int lt2) {
    f32x4 acc[4][4] = {};
    const unsigned short* Ap = &Ab[lt2 & 3][lane * 8];
    #pragma unroll
    for (int kt = 0; kt < 8; kt++) {
      bf16x8 af[4];
      #pragma unroll
      for (int mt = 0; mt < 4; mt++)
        af[mt] = *(const bf16x8*)(Ap + (mt * 8 + kt) * 512);
      #pragma unroll
      for (int n = 0; n < 4; n++)
        #pragma unroll
        for (int mt = 0; mt < 4; mt++)
          acc[mt][n] = __builtin_amdgcn_mfma_f32_16x16x32_bf16(af[mt], bq[n][kt], acc[mt][n], 0, 0, 0);
    }

    // epilogue: relu(h+c)*w2 summed over my 4 col-tiles -> 16 independent values
    float vs[16];
    #pragma unroll
    for (int mt = 0; mt < 4; mt++)
      #pragma unroll
      for (int r = 0; r < 4; r++) {
        float v = 0.f;
        #pragma unroll
        for (int n = 0; n < 4; n++) {
          float h = acc[mt][n][r] + cj[n];
          v += fmaxf(h, 0.f) * w2j[n];
        }
        vs[mt * 4 + r] = v;
      }
    // 16-lane rotate-butterfly on the VALU pipe (DPP row_ror), 16-wide ILP/stage
    DPP_STAGE(0x128)   // ror 8
    DPP_STAGE(0x124)   // ror 4
    DPP_STAGE(0x122)   // ror 2
    DPP_STAGE(0x121)   // ror 1
    if (l16 == 0) {
      #pragma unroll
      for (int mt = 0; mt < 4; mt++)
        #pragma unroll
        for (int r = 0; r < 4; r++)
          partial[lt2 & 3][w][mt * 16 + quad * 4 + r] = vs[mt * 4 + r];
    }
  };

  // ---- prologue: stage tiles 0,1 ----
  stage(0, 0);
  if (1 < ntl) stage(1, 1);

  // ---- main loop: one barrier per PAIR of tiles ----
  for (int lt = 0; lt < ntl; lt += 2) {
    __syncthreads();   // drains own DMAs (issued a full pair ago), syncs partial ring

    int s2 = lt + 2, s3 = lt + 3;
    if (s2 < ntl) stage(s2, s2 & 3);
    if (s3 < ntl) stage(s3, s3 & 3);

    if (lt >= 2) {
      if (tid < 64)       combine(lt - 2, tid);
      else if (tid < 128) combine(lt - 1, tid - 64);
    }

    compute_tile(lt);
    if (lt + 1 < ntl) compute_tile(lt + 1);
  }

  // ---- tail: combine the last pair ----
  __syncthreads();
  if ((ntl & 1) == 0) {
    if (tid < 64)       combine(ntl - 2, tid);
    else if (tid < 128) combine(ntl - 1, tid - 64);
  } else {
    if (tid < 64)       combine(ntl - 1, tid);
  }
}

extern "C" void kernel_launch(void* const* d_in, const int* in_sizes, int n_in,
                              void* d_out, int out_size, void* d_ws, size_t ws_size,
                              hipStream_t stream) {
  const float* node_feat = (const float*)d_in[0];
  const int*   eidx      = (const int*)d_in[1];
  const float* W1        = (const float*)d_in[2];
  const float* b1        = (const float*)d_in[3];
  const float* gamma     = (const float*)d_in[4];
  const float* beta      = (const float*)d_in[5];
  const float* mean      = (const float*)d_in[6];
  const float* var       = (const float*)d_in[7];
  const float* W2        = (const float*)d_in[8];
  const float* b2        = (const float*)d_in[9];
  float* out = (float*)d_out;

  // Workspace: Wswz bf16[512*256] (256KB) | cbias f32[512] | w2c f32[512]
  //          | nfb bf16[50000*128] (12.8MB)
  unsigned short* Wswz = (unsigned short*)d_ws;
  float* cbias = (float*)((char*)d_ws + (size_t)HDIM * KDIM * 2);
  float* w2c   = cbias + HDIM;
  unsigned short* nfb = (unsigned short*)(w2c + HDIM);

  void* args[] = {(void*)&node_feat, (void*)&eidx, (void*)&W1, (void*)&b1,
                  (void*)&gamma, (void*)&beta, (void*)&mean, (void*)&var,
                  (void*)&W2, (void*)&b2, (void*)&Wswz, (void*)&cbias,
                  (void*)&w2c, (void*)&nfb, (void*)&out};
  hipLaunchCooperativeKernel((void*)edge_mlp_fused_kernel, dim3(NBLK), dim3(512),
                             args, 0, stream);
}